// Round 1
// baseline (1541.952 us; speedup 1.0000x reference)
//
#include <hip/hip_runtime.h>
#include <math.h>

// Problem constants (from reference):
//   WH=WW=16, N=256 tokens/window, H=6 heads, DIM=192, hd=32
//   B_=256 windows, nW=64 mask windows, qk_scale = 32^-0.5
#define N_TOK 256
#define NHEADS 6
#define DIM_C 192
#define HD 32
#define B_WIN 256

// ---------------------------------------------------------------------------
// Kernel 1: continuous relative position bias MLP -> table (961 x 6)
// table[e][head] = b2[head] + sum_t w2[head][t] * relu(w1[t]. [t0,t1,s0,s1] + b1[t])
// e = i*31+j, t0=(i-15)/15*8, t1=(j-15)/15*8
// ---------------------------------------------------------------------------
__global__ __launch_bounds__(512) void cpb_table_kernel(
    const float* __restrict__ scale, const float* __restrict__ w1,
    const float* __restrict__ b1, const float* __restrict__ w2,
    const float* __restrict__ b2, float* __restrict__ table)
{
    __shared__ float red[512];
    const int e = blockIdx.x;            // 0..960
    const int i = e / 31, j = e % 31;
    const float t0 = ((float)(i - 15)) * (8.0f / 15.0f);
    const float t1 = ((float)(j - 15)) * (8.0f / 15.0f);
    const float s0 = scale[0], s1 = scale[1];
    const int t = threadIdx.x;
    const float* w = w1 + t * 4;
    float h = w[0] * t0 + w[1] * t1 + w[2] * s0 + w[3] * s1 + b1[t];
    h = fmaxf(h, 0.0f);
    for (int head = 0; head < NHEADS; ++head) {
        red[t] = h * w2[head * 512 + t];
        __syncthreads();
        for (int s = 256; s > 0; s >>= 1) {
            if (t < s) red[t] += red[t + s];
            __syncthreads();
        }
        if (t == 0) table[e * NHEADS + head] = red[0] + b2[head];
        __syncthreads();
    }
}

// ---------------------------------------------------------------------------
// Kernel 2: expand table -> bias_full (6, 256, 256) using inline rel-pos index
// ---------------------------------------------------------------------------
__global__ __launch_bounds__(256) void bias_expand_kernel(
    const float* __restrict__ table, float* __restrict__ bias_full)
{
    const int g = blockIdx.x * 256 + threadIdx.x;   // < 6*65536
    const int h = g >> 16;
    const int r = g & 65535;
    const int i = r >> 8, j = r & 255;
    const int rel0 = (i >> 4) - (j >> 4) + 15;
    const int rel1 = (i & 15) - (j & 15) + 15;
    bias_full[g] = table[(rel0 * 31 + rel1) * NHEADS + h];
}

// ---------------------------------------------------------------------------
// Kernels 3/5: tiled fp32 GEMM  C(M,Nout) = A(M,192) * W(Nout,192)^T + bias
// 64x64 tile, BK=16, 256 threads, 4x4 per thread.
// MODE 0: QKV epilogue -> scatter into q/k/v (B,H,N,hd); q pre-scaled.
// MODE 1: proj epilogue -> direct write.
// ---------------------------------------------------------------------------
template <int MODE>
__global__ __launch_bounds__(256) void gemm_bt_kernel(
    const float* __restrict__ A, const float* __restrict__ W,
    const float* __restrict__ bias,
    float* __restrict__ out0, float* __restrict__ out1, float* __restrict__ out2)
{
    __shared__ float As[16][64];
    __shared__ float Bs[16][64];
    const int t = threadIdx.x;
    const int m0 = blockIdx.y * 64;
    const int n0 = blockIdx.x * 64;
    const int lm = t >> 2;            // 0..63  (row within tile for loads)
    const int lk = (t & 3) << 2;      // 0,4,8,12
    const int ty = t >> 4;            // 0..15 (m)
    const int tx = t & 15;            // 0..15 (n)
    float acc[4][4] = {};
    const float* Arow = A + (size_t)(m0 + lm) * DIM_C + lk;
    const float* Wrow = W + (size_t)(n0 + lm) * DIM_C + lk;

    for (int k0 = 0; k0 < DIM_C; k0 += 16) {
        float4 av = *(const float4*)(Arow + k0);
        float4 wv = *(const float4*)(Wrow + k0);
        __syncthreads();
        As[lk + 0][lm] = av.x; As[lk + 1][lm] = av.y;
        As[lk + 2][lm] = av.z; As[lk + 3][lm] = av.w;
        Bs[lk + 0][lm] = wv.x; Bs[lk + 1][lm] = wv.y;
        Bs[lk + 2][lm] = wv.z; Bs[lk + 3][lm] = wv.w;
        __syncthreads();
#pragma unroll
        for (int kk = 0; kk < 16; ++kk) {
            float4 a = ((const float4*)&As[kk][0])[ty];
            float4 b = ((const float4*)&Bs[kk][0])[tx];
            acc[0][0] += a.x * b.x; acc[0][1] += a.x * b.y; acc[0][2] += a.x * b.z; acc[0][3] += a.x * b.w;
            acc[1][0] += a.y * b.x; acc[1][1] += a.y * b.y; acc[1][2] += a.y * b.z; acc[1][3] += a.y * b.w;
            acc[2][0] += a.z * b.x; acc[2][1] += a.z * b.y; acc[2][2] += a.z * b.z; acc[2][3] += a.z * b.w;
            acc[3][0] += a.w * b.x; acc[3][1] += a.w * b.y; acc[3][2] += a.w * b.z; acc[3][3] += a.w * b.w;
        }
    }

    const float qk_scale = 0.17677669529663689f;  // 32^-0.5
#pragma unroll
    for (int ii = 0; ii < 4; ++ii) {
#pragma unroll
        for (int jj = 0; jj < 4; ++jj) {
            const int m = m0 + ty * 4 + ii;
            const int c = n0 + tx * 4 + jj;
            float val = acc[ii][jj] + bias[c];
            if (MODE == 0) {
                const int which = c / DIM_C;
                const int rem = c - which * DIM_C;
                const int h = rem >> 5, d = rem & 31;
                const int b = m >> 8, tok = m & 255;
                const size_t dst = ((size_t)((b * NHEADS + h) * N_TOK + tok)) * HD + d;
                if (which == 0)      out0[dst] = val * qk_scale;
                else if (which == 1) out1[dst] = val;
                else                 out2[dst] = val;
            } else {
                out0[(size_t)m * DIM_C + c] = val;
            }
        }
    }
}

// ---------------------------------------------------------------------------
// Kernel 4: attention per (b,h). K/V in LDS, thread-per-query-row,
// two-pass softmax (max, then exp/accumulate). Writes (B,N,C) layout.
// ---------------------------------------------------------------------------
__global__ __launch_bounds__(256) void attn_kernel(
    const float* __restrict__ q, const float* __restrict__ k,
    const float* __restrict__ v, const float* __restrict__ bias_full,
    const float* __restrict__ mask, float* __restrict__ out)
{
    __shared__ float4 Ks[N_TOK * 8];   // 32 KB
    __shared__ float4 Vs[N_TOK * 8];   // 32 KB
    const int h = blockIdx.x;          // 0..5
    const int b = blockIdx.y;          // 0..255
    const size_t slab = ((size_t)(b * NHEADS + h)) * N_TOK * HD;
    const float4* kg = (const float4*)(k + slab);
    const float4* vg = (const float4*)(v + slab);
    const int t = threadIdx.x;
#pragma unroll
    for (int u = 0; u < 8; ++u) {
        Ks[u * 256 + t] = kg[u * 256 + t];
        Vs[u * 256 + t] = vg[u * 256 + t];
    }
    __syncthreads();

    float4 qr[8];
    const float4* qg = (const float4*)(q + slab + (size_t)t * HD);
#pragma unroll
    for (int u = 0; u < 8; ++u) qr[u] = qg[u];

    const float* brow = bias_full + h * 65536 + t * 256;
    const float* mrow = mask + (size_t)(b & 63) * 65536 + t * 256;

    // pass 1: row max
    float mmax = -1e30f;
    for (int j = 0; j < N_TOK; ++j) {
        const float4* kj = &Ks[j * 8];
        float s = 0.0f;
#pragma unroll
        for (int u = 0; u < 8; ++u) {
            float4 kv = kj[u];
            s += qr[u].x * kv.x + qr[u].y * kv.y + qr[u].z * kv.z + qr[u].w * kv.w;
        }
        s += brow[j] + mrow[j];
        mmax = fmaxf(mmax, s);
    }

    // pass 2: exp + accumulate
    float l = 0.0f;
    float4 o4[8] = {};
    for (int j = 0; j < N_TOK; ++j) {
        const float4* kj = &Ks[j * 8];
        float s = 0.0f;
#pragma unroll
        for (int u = 0; u < 8; ++u) {
            float4 kv = kj[u];
            s += qr[u].x * kv.x + qr[u].y * kv.y + qr[u].z * kv.z + qr[u].w * kv.w;
        }
        s += brow[j] + mrow[j];
        const float p = __expf(s - mmax);
        l += p;
        const float4* vj = &Vs[j * 8];
#pragma unroll
        for (int u = 0; u < 8; ++u) {
            float4 vv = vj[u];
            o4[u].x += p * vv.x; o4[u].y += p * vv.y;
            o4[u].z += p * vv.z; o4[u].w += p * vv.w;
        }
    }

    const float inv = 1.0f / l;
    float* dst = out + ((size_t)(b * N_TOK + t)) * DIM_C + h * HD;
#pragma unroll
    for (int u = 0; u < 8; ++u) {
        float4 val = o4[u];
        val.x *= inv; val.y *= inv; val.z *= inv; val.w *= inv;
        ((float4*)dst)[u] = val;
    }
}

// ---------------------------------------------------------------------------
// Launch
// ---------------------------------------------------------------------------
extern "C" void kernel_launch(void* const* d_in, const int* in_sizes, int n_in,
                              void* d_out, int out_size, void* d_ws, size_t ws_size,
                              hipStream_t stream)
{
    const float* x      = (const float*)d_in[0];   // (256,256,192)
    const float* scale  = (const float*)d_in[1];   // (1,2)
    const float* mask   = (const float*)d_in[2];   // (64,256,256)
    const float* qkv_w  = (const float*)d_in[3];   // (576,192)
    const float* qkv_b  = (const float*)d_in[4];   // (576,)
    const float* cpb_w1 = (const float*)d_in[5];   // (512,4)
    const float* cpb_b1 = (const float*)d_in[6];   // (512,)
    const float* cpb_w2 = (const float*)d_in[7];   // (6,512)
    const float* cpb_b2 = (const float*)d_in[8];   // (6,)
    const float* proj_w = (const float*)d_in[9];   // (192,192)
    const float* proj_b = (const float*)d_in[10];  // (192,)
    float* out = (float*)d_out;                    // (256,256,192)

    // Workspace layout (floats): q,k,v (B,H,N,hd) + attn_out (B,N,C) + table + bias
    const size_t per_qkv = (size_t)B_WIN * NHEADS * N_TOK * HD;  // 12,582,912
    float* wsf      = (float*)d_ws;
    float* qbuf     = wsf;
    float* kbuf     = qbuf + per_qkv;
    float* vbuf     = kbuf + per_qkv;
    float* attn_out = vbuf + per_qkv;
    float* table    = attn_out + per_qkv;          // 961*6
    float* biasfull = table + 961 * NHEADS;        // 6*65536

    // 1. CPB MLP -> table (961 x 6)
    cpb_table_kernel<<<961, 512, 0, stream>>>(scale, cpb_w1, cpb_b1, cpb_w2, cpb_b2, table);

    // 2. expand -> bias_full (6,256,256)
    bias_expand_kernel<<<(NHEADS * 65536) / 256, 256, 0, stream>>>(table, biasfull);

    // 3. QKV GEMM: (65536,192) x (576,192)^T, scatter into q/k/v
    gemm_bt_kernel<0><<<dim3(576 / 64, (B_WIN * N_TOK) / 64), 256, 0, stream>>>(
        x, qkv_w, qkv_b, qbuf, kbuf, vbuf);

    // 4. attention per (b,h)
    attn_kernel<<<dim3(NHEADS, B_WIN), 256, 0, stream>>>(
        qbuf, kbuf, vbuf, biasfull, mask, attn_out);

    // 5. proj GEMM: (65536,192) x (192,192)^T -> out
    gemm_bt_kernel<1><<<dim3(DIM_C / 64, (B_WIN * N_TOK) / 64), 256, 0, stream>>>(
        attn_out, proj_w, proj_b, out, nullptr, nullptr);
}

// Round 2
// 1106.574 us; speedup vs baseline: 1.3934x; 1.3934x over previous
//
#include <hip/hip_runtime.h>
#include <math.h>

// Problem constants:
//   WH=WW=16, N=256 tokens/window, H=6 heads, DIM=192, hd=32
//   B_=256 windows, nW=64 mask windows, qk_scale = 32^-0.5
#define N_TOK 256
#define NHEADS 6
#define DIM_C 192
#define HD 32
#define B_WIN 256

typedef short bf16x8 __attribute__((ext_vector_type(8)));   // 8 bf16 in 4 VGPRs
typedef float f32x4 __attribute__((ext_vector_type(4)));

// fp32 -> bf16 (RNE), bit-level so it works regardless of __bf16 support
__device__ inline short f2bf(float f) {
    unsigned u = __float_as_uint(f);
    u = (u + 0x7fffu + ((u >> 16) & 1u)) >> 16;
    return (short)u;
}
__device__ inline bf16x8 to_bf16x8(float4 a, float4 b) {
    bf16x8 r;
    r[0] = f2bf(a.x); r[1] = f2bf(a.y); r[2] = f2bf(a.z); r[3] = f2bf(a.w);
    r[4] = f2bf(b.x); r[5] = f2bf(b.y); r[6] = f2bf(b.z); r[7] = f2bf(b.w);
    return r;
}

// ---------------------------------------------------------------------------
// Kernel 1: CPB MLP -> table (961 x 6)
// ---------------------------------------------------------------------------
__global__ __launch_bounds__(512) void cpb_table_kernel(
    const float* __restrict__ scale, const float* __restrict__ w1,
    const float* __restrict__ b1, const float* __restrict__ w2,
    const float* __restrict__ b2, float* __restrict__ table)
{
    __shared__ float red[512];
    const int e = blockIdx.x;            // 0..960
    const int i = e / 31, j = e % 31;
    const float t0 = ((float)(i - 15)) * (8.0f / 15.0f);
    const float t1 = ((float)(j - 15)) * (8.0f / 15.0f);
    const float s0 = scale[0], s1 = scale[1];
    const int t = threadIdx.x;
    const float* w = w1 + t * 4;
    float h = w[0] * t0 + w[1] * t1 + w[2] * s0 + w[3] * s1 + b1[t];
    h = fmaxf(h, 0.0f);
    for (int head = 0; head < NHEADS; ++head) {
        red[t] = h * w2[head * 512 + t];
        __syncthreads();
        for (int s = 256; s > 0; s >>= 1) {
            if (t < s) red[t] += red[t + s];
            __syncthreads();
        }
        if (t == 0) table[e * NHEADS + head] = red[0] + b2[head];
        __syncthreads();
    }
}

// ---------------------------------------------------------------------------
// Kernel 2: expand table -> bias_full (6, 256, 256)
// ---------------------------------------------------------------------------
__global__ __launch_bounds__(256) void bias_expand_kernel(
    const float* __restrict__ table, float* __restrict__ bias_full)
{
    const int g = blockIdx.x * 256 + threadIdx.x;   // < 6*65536
    const int h = g >> 16;
    const int r = g & 65535;
    const int i = r >> 8, j = r & 255;
    const int rel0 = (i >> 4) - (j >> 4) + 15;
    const int rel1 = (i & 15) - (j & 15) + 15;
    bias_full[g] = table[(rel0 * 31 + rel1) * NHEADS + h];
}

// ---------------------------------------------------------------------------
// Kernels 3/5: tiled fp32 GEMM  C(M,Nout) = A(M,192) * W(Nout,192)^T + bias
// ---------------------------------------------------------------------------
template <int MODE>
__global__ __launch_bounds__(256) void gemm_bt_kernel(
    const float* __restrict__ A, const float* __restrict__ W,
    const float* __restrict__ bias,
    float* __restrict__ out0, float* __restrict__ out1, float* __restrict__ out2)
{
    __shared__ float As[16][64];
    __shared__ float Bs[16][64];
    const int t = threadIdx.x;
    const int m0 = blockIdx.y * 64;
    const int n0 = blockIdx.x * 64;
    const int lm = t >> 2;
    const int lk = (t & 3) << 2;
    const int ty = t >> 4;
    const int tx = t & 15;
    float acc[4][4] = {};
    const float* Arow = A + (size_t)(m0 + lm) * DIM_C + lk;
    const float* Wrow = W + (size_t)(n0 + lm) * DIM_C + lk;

    for (int k0 = 0; k0 < DIM_C; k0 += 16) {
        float4 av = *(const float4*)(Arow + k0);
        float4 wv = *(const float4*)(Wrow + k0);
        __syncthreads();
        As[lk + 0][lm] = av.x; As[lk + 1][lm] = av.y;
        As[lk + 2][lm] = av.z; As[lk + 3][lm] = av.w;
        Bs[lk + 0][lm] = wv.x; Bs[lk + 1][lm] = wv.y;
        Bs[lk + 2][lm] = wv.z; Bs[lk + 3][lm] = wv.w;
        __syncthreads();
#pragma unroll
        for (int kk = 0; kk < 16; ++kk) {
            float4 a = ((const float4*)&As[kk][0])[ty];
            float4 b = ((const float4*)&Bs[kk][0])[tx];
            acc[0][0] += a.x * b.x; acc[0][1] += a.x * b.y; acc[0][2] += a.x * b.z; acc[0][3] += a.x * b.w;
            acc[1][0] += a.y * b.x; acc[1][1] += a.y * b.y; acc[1][2] += a.y * b.z; acc[1][3] += a.y * b.w;
            acc[2][0] += a.z * b.x; acc[2][1] += a.z * b.y; acc[2][2] += a.z * b.z; acc[2][3] += a.z * b.w;
            acc[3][0] += a.w * b.x; acc[3][1] += a.w * b.y; acc[3][2] += a.w * b.z; acc[3][3] += a.w * b.w;
        }
    }

    const float qk_scale = 0.17677669529663689f;  // 32^-0.5
#pragma unroll
    for (int ii = 0; ii < 4; ++ii) {
#pragma unroll
        for (int jj = 0; jj < 4; ++jj) {
            const int m = m0 + ty * 4 + ii;
            const int c = n0 + tx * 4 + jj;
            float val = acc[ii][jj] + bias[c];
            if (MODE == 0) {
                const int which = c / DIM_C;
                const int rem = c - which * DIM_C;
                const int h = rem >> 5, d = rem & 31;
                const int b = m >> 8, tok = m & 255;
                const size_t dst = ((size_t)((b * NHEADS + h) * N_TOK + tok)) * HD + d;
                if (which == 0)      out0[dst] = val * qk_scale;
                else if (which == 1) out1[dst] = val;
                else                 out2[dst] = val;
            } else {
                out0[(size_t)m * DIM_C + c] = val;
            }
        }
    }
}

// ---------------------------------------------------------------------------
// Kernel 4: MFMA attention per (b,h). 256 threads = 4 waves.
// Wave w owns score columns [w*64, w*64+64). Rows processed in 4 chunks of 64.
// Two-pass softmax: register C-layout scores, shfl_xor butterflies + LDS
// cross-wave combine. P (bf16) -> LDS (padded LD=264) -> MFMA PV.
// ---------------------------------------------------------------------------
#define PS_LD 264   // 256 + 8 bf16 pad: frag reads land 2 lanes/bank (free)

__global__ __launch_bounds__(256) void attn_mfma_kernel(
    const float* __restrict__ q, const float* __restrict__ k,
    const float* __restrict__ v, const float* __restrict__ bias_full,
    const float* __restrict__ mask, float* __restrict__ out)
{
    __shared__ __align__(16) short Vt[32][PS_LD];   // V^T  [d][token], bf16
    __shared__ __align__(16) short Ps[64][PS_LD];   // P chunk, bf16
    __shared__ __align__(16) float rowred[64][4];   // per-wave row maxima
    __shared__ __align__(16) float rowsum[64][4];   // per-wave row sums

    const int h = blockIdx.x;            // 0..5
    const int b = blockIdx.y;            // 0..255
    const int t = threadIdx.x;
    const int lane = t & 63;
    const int w = t >> 6;                // wave id 0..3
    const int l15 = lane & 15;
    const int quad = lane >> 4;
    const size_t slab = ((size_t)(b * NHEADS + h)) * (N_TOK * HD);

    // ---- stage V transposed into LDS (bf16): thread t handles V row t ----
    {
        const float4* vrow = (const float4*)(v + slab + (size_t)t * HD);
#pragma unroll
        for (int u = 0; u < 8; ++u) {
            float4 vv = vrow[u];
            Vt[u * 4 + 0][t] = f2bf(vv.x);
            Vt[u * 4 + 1][t] = f2bf(vv.y);
            Vt[u * 4 + 2][t] = f2bf(vv.z);
            Vt[u * 4 + 3][t] = f2bf(vv.w);
        }
    }

    // ---- K fragments: registers for the whole kernel (wave's 64 K-rows) ----
    bf16x8 kf[4];
#pragma unroll
    for (int nt = 0; nt < 4; ++nt) {
        const float4* kp = (const float4*)(k + slab + (size_t)(w * 64 + nt * 16 + l15) * HD + quad * 8);
        kf[nt] = to_bf16x8(kp[0], kp[1]);
    }
    __syncthreads();

    const float* biasH = bias_full + h * 65536;
    const float* maskW = mask + (size_t)(b & 63) * 65536;

    for (int chunk = 0; chunk < 4; ++chunk) {
        const int c0 = chunk * 64;

        // Q fragments for this chunk (direct from global, coalesced)
        bf16x8 qf[4];
#pragma unroll
        for (int mt = 0; mt < 4; ++mt) {
            const float4* qp = (const float4*)(q + slab + (size_t)(c0 + mt * 16 + l15) * HD + quad * 8);
            qf[mt] = to_bf16x8(qp[0], qp[1]);
        }

        // QK^T: 16 MFMAs -> S in C-layout regs (row = mt*16+quad*4+r, col = w*64+nt*16+l15)
        f32x4 S[4][4];
#pragma unroll
        for (int mt = 0; mt < 4; ++mt)
#pragma unroll
            for (int nt = 0; nt < 4; ++nt) {
                f32x4 z = {0.f, 0.f, 0.f, 0.f};
                S[mt][nt] = __builtin_amdgcn_mfma_f32_16x16x32_bf16(qf[mt], kf[nt], z, 0, 0, 0);
            }

        // bias + mask + per-wave row max
#pragma unroll
        for (int mt = 0; mt < 4; ++mt) {
#pragma unroll
            for (int r = 0; r < 4; ++r) {
                const int row = c0 + mt * 16 + quad * 4 + r;
                const int colb = w * 64 + l15;
                float m4 = -1e30f;
#pragma unroll
                for (int nt = 0; nt < 4; ++nt) {
                    const int idx = row * 256 + colb + nt * 16;
                    float sval = S[mt][nt][r] + biasH[idx] + maskW[idx];
                    S[mt][nt][r] = sval;
                    m4 = fmaxf(m4, sval);
                }
                m4 = fmaxf(m4, __shfl_xor(m4, 1));
                m4 = fmaxf(m4, __shfl_xor(m4, 2));
                m4 = fmaxf(m4, __shfl_xor(m4, 4));
                m4 = fmaxf(m4, __shfl_xor(m4, 8));
                if (l15 == 0) rowred[mt * 16 + quad * 4 + r][w] = m4;
            }
        }
        __syncthreads();

        // exp + per-wave row sum + write P (bf16) to LDS
#pragma unroll
        for (int mt = 0; mt < 4; ++mt) {
#pragma unroll
            for (int r = 0; r < 4; ++r) {
                const int lrow = mt * 16 + quad * 4 + r;
                float4 mr = *(const float4*)rowred[lrow];
                const float rm = fmaxf(fmaxf(mr.x, mr.y), fmaxf(mr.z, mr.w));
                float s4 = 0.0f;
#pragma unroll
                for (int nt = 0; nt < 4; ++nt) {
                    const float p = __expf(S[mt][nt][r] - rm);
                    s4 += p;
                    Ps[lrow][w * 64 + nt * 16 + l15] = f2bf(p);
                }
                s4 += __shfl_xor(s4, 1);
                s4 += __shfl_xor(s4, 2);
                s4 += __shfl_xor(s4, 4);
                s4 += __shfl_xor(s4, 8);
                if (l15 == 0) rowsum[lrow][w] = s4;
            }
        }
        __syncthreads();

        // PV: wave w -> m-tile w (rows w*16..w*16+15), n-tiles 0,1 (d 0..31)
        f32x4 O0 = {0.f, 0.f, 0.f, 0.f};
        f32x4 O1 = {0.f, 0.f, 0.f, 0.f};
#pragma unroll
        for (int ks = 0; ks < 8; ++ks) {
            bf16x8 af  = *(const bf16x8*)&Ps[w * 16 + l15][ks * 32 + quad * 8];
            bf16x8 bf0 = *(const bf16x8*)&Vt[l15][ks * 32 + quad * 8];
            bf16x8 bf1 = *(const bf16x8*)&Vt[16 + l15][ks * 32 + quad * 8];
            O0 = __builtin_amdgcn_mfma_f32_16x16x32_bf16(af, bf0, O0, 0, 0, 0);
            O1 = __builtin_amdgcn_mfma_f32_16x16x32_bf16(af, bf1, O1, 0, 0, 0);
        }

        // epilogue: divide by row sum, write (B, N, C) layout
#pragma unroll
        for (int r = 0; r < 4; ++r) {
            const int lrow = w * 16 + quad * 4 + r;
            float4 sr = *(const float4*)rowsum[lrow];
            const float inv = 1.0f / (sr.x + sr.y + sr.z + sr.w);
            const int token = c0 + lrow;
            float* dst = out + ((size_t)(b * N_TOK + token)) * DIM_C + h * HD;
            dst[l15]      = O0[r] * inv;
            dst[16 + l15] = O1[r] * inv;
        }
        __syncthreads();   // protect Ps/rowred/rowsum before next chunk
    }
}

// ---------------------------------------------------------------------------
// Launch
// ---------------------------------------------------------------------------
extern "C" void kernel_launch(void* const* d_in, const int* in_sizes, int n_in,
                              void* d_out, int out_size, void* d_ws, size_t ws_size,
                              hipStream_t stream)
{
    const float* x      = (const float*)d_in[0];   // (256,256,192)
    const float* scale  = (const float*)d_in[1];   // (1,2)
    const float* mask   = (const float*)d_in[2];   // (64,256,256)
    const float* qkv_w  = (const float*)d_in[3];   // (576,192)
    const float* qkv_b  = (const float*)d_in[4];   // (576,)
    const float* cpb_w1 = (const float*)d_in[5];   // (512,4)
    const float* cpb_b1 = (const float*)d_in[6];   // (512,)
    const float* cpb_w2 = (const float*)d_in[7];   // (6,512)
    const float* cpb_b2 = (const float*)d_in[8];   // (6,)
    const float* proj_w = (const float*)d_in[9];   // (192,192)
    const float* proj_b = (const float*)d_in[10];  // (192,)
    float* out = (float*)d_out;                    // (256,256,192)

    const size_t per_qkv = (size_t)B_WIN * NHEADS * N_TOK * HD;  // 12,582,912
    float* wsf      = (float*)d_ws;
    float* qbuf     = wsf;
    float* kbuf     = qbuf + per_qkv;
    float* vbuf     = kbuf + per_qkv;
    float* attn_out = vbuf + per_qkv;
    float* table    = attn_out + per_qkv;          // 961*6
    float* biasfull = table + 961 * NHEADS;        // 6*65536

    cpb_table_kernel<<<961, 512, 0, stream>>>(scale, cpb_w1, cpb_b1, cpb_w2, cpb_b2, table);

    bias_expand_kernel<<<(NHEADS * 65536) / 256, 256, 0, stream>>>(table, biasfull);

    gemm_bt_kernel<0><<<dim3(576 / 64, (B_WIN * N_TOK) / 64), 256, 0, stream>>>(
        x, qkv_w, qkv_b, qbuf, kbuf, vbuf);

    attn_mfma_kernel<<<dim3(NHEADS, B_WIN), 256, 0, stream>>>(
        qbuf, kbuf, vbuf, biasfull, mask, attn_out);

    gemm_bt_kernel<1><<<dim3(DIM_C / 64, (B_WIN * N_TOK) / 64), 256, 0, stream>>>(
        attn_out, proj_w, proj_b, out, nullptr, nullptr);
}

// Round 3
// 691.676 us; speedup vs baseline: 2.2293x; 1.5998x over previous
//
#include <hip/hip_runtime.h>
#include <math.h>

// Problem constants:
//   WH=WW=16, N=256 tokens/window, H=6 heads, DIM=192, hd=32
//   B_=256 windows, nW=64 mask windows, qk_scale = 32^-0.5
#define N_TOK 256
#define NHEADS 6
#define DIM_C 192
#define HD 32
#define B_WIN 256

typedef short bf16x8 __attribute__((ext_vector_type(8)));   // 8 bf16 in 4 VGPRs
typedef float f32x4 __attribute__((ext_vector_type(4)));

__device__ inline short f2bf(float f) {
    unsigned u = __float_as_uint(f);
    u = (u + 0x7fffu + ((u >> 16) & 1u)) >> 16;
    return (short)u;
}
__device__ inline float bf2f(short s) {
    return __uint_as_float(((unsigned)(unsigned short)s) << 16);
}
__device__ inline bf16x8 to_bf16x8(float4 a, float4 b) {
    bf16x8 r;
    r[0] = f2bf(a.x); r[1] = f2bf(a.y); r[2] = f2bf(a.z); r[3] = f2bf(a.w);
    r[4] = f2bf(b.x); r[5] = f2bf(b.y); r[6] = f2bf(b.z); r[7] = f2bf(b.w);
    return r;
}

// ---------------------------------------------------------------------------
// Kernel 1: CPB MLP -> table (961 x 6) fp32
// ---------------------------------------------------------------------------
__global__ __launch_bounds__(512) void cpb_table_kernel(
    const float* __restrict__ scale, const float* __restrict__ w1,
    const float* __restrict__ b1, const float* __restrict__ w2,
    const float* __restrict__ b2, float* __restrict__ table)
{
    __shared__ float red[512];
    const int e = blockIdx.x;            // 0..960
    const int i = e / 31, j = e % 31;
    const float t0 = ((float)(i - 15)) * (8.0f / 15.0f);
    const float t1 = ((float)(j - 15)) * (8.0f / 15.0f);
    const float s0 = scale[0], s1 = scale[1];
    const int t = threadIdx.x;
    const float* w = w1 + t * 4;
    float h = w[0] * t0 + w[1] * t1 + w[2] * s0 + w[3] * s1 + b1[t];
    h = fmaxf(h, 0.0f);
    for (int head = 0; head < NHEADS; ++head) {
        red[t] = h * w2[head * 512 + t];
        __syncthreads();
        for (int s = 256; s > 0; s >>= 1) {
            if (t < s) red[t] += red[t + s];
            __syncthreads();
        }
        if (t == 0) table[e * NHEADS + head] = red[0] + b2[head];
        __syncthreads();
    }
}

// ---------------------------------------------------------------------------
// Kernel 2: expand table -> bias16 (6, 256, 256) bf16
// ---------------------------------------------------------------------------
__global__ __launch_bounds__(256) void bias_expand_kernel(
    const float* __restrict__ table, short* __restrict__ bias16)
{
    const int g = blockIdx.x * 256 + threadIdx.x;   // < 6*65536
    const int h = g >> 16;
    const int r = g & 65535;
    const int i = r >> 8, j = r & 255;
    const int rel0 = (i >> 4) - (j >> 4) + 15;
    const int rel1 = (i & 15) - (j & 15) + 15;
    bias16[g] = f2bf(table[(rel0 * 31 + rel1) * NHEADS + h]);
}

// ---------------------------------------------------------------------------
// Kernel 2b: generic fp32 -> bf16 (n multiple of 4)
// ---------------------------------------------------------------------------
__global__ __launch_bounds__(256) void f32_to_bf16_kernel(
    const float* __restrict__ in, short* __restrict__ out, int n4)
{
    const int i = blockIdx.x * 256 + threadIdx.x;
    if (i < n4) {
        float4 v = ((const float4*)in)[i];
        short4 s;
        s.x = f2bf(v.x); s.y = f2bf(v.y); s.z = f2bf(v.z); s.w = f2bf(v.w);
        ((short4*)out)[i] = s;
    }
}

// ---------------------------------------------------------------------------
// Kernel 3: QKV GEMM via MFMA, no LDS. C(65536,576) = x(65536,192) * W^T + b.
// Block = 4 waves; wave w owns rows m0+w*32..+31; n-tile 64 wide.
// A (x) fp32 from global (convert in regs); W pre-converted bf16 (L2-hot).
// Epilogue scatters bf16 into q/k/v (B,H,N,hd); q pre-scaled.
// ---------------------------------------------------------------------------
__global__ __launch_bounds__(256) void qkv_gemm_kernel(
    const float* __restrict__ x, const short* __restrict__ w16,
    const float* __restrict__ qkv_b,
    short* __restrict__ qb, short* __restrict__ kb, short* __restrict__ vb)
{
    const int t = threadIdx.x;
    const int lane = t & 63;
    const int w = t >> 6;
    const int l15 = lane & 15, quad = lane >> 4;
    const int n0 = blockIdx.x * 64;
    const int m0 = blockIdx.y * 128 + w * 32;

    f32x4 acc[2][4] = {};
#pragma unroll
    for (int ks = 0; ks < 6; ++ks) {
        bf16x8 af[2];
#pragma unroll
        for (int mt = 0; mt < 2; ++mt) {
            const float4* ap = (const float4*)(x + (size_t)(m0 + mt * 16 + l15) * DIM_C + ks * 32 + quad * 8);
            af[mt] = to_bf16x8(ap[0], ap[1]);
        }
        bf16x8 bfr[4];
#pragma unroll
        for (int nt = 0; nt < 4; ++nt)
            bfr[nt] = *(const bf16x8*)(w16 + (size_t)(n0 + nt * 16 + l15) * DIM_C + ks * 32 + quad * 8);
#pragma unroll
        for (int mt = 0; mt < 2; ++mt)
#pragma unroll
            for (int nt = 0; nt < 4; ++nt)
                acc[mt][nt] = __builtin_amdgcn_mfma_f32_16x16x32_bf16(af[mt], bfr[nt], acc[mt][nt], 0, 0, 0);
    }

    const int which = n0 / DIM_C;                   // constant per block (64 | 192)
    short* outp = (which == 0) ? qb : (which == 1) ? kb : vb;
    const float qscale = (which == 0) ? 0.17677669529663689f : 1.0f;
#pragma unroll
    for (int mt = 0; mt < 2; ++mt) {
#pragma unroll
        for (int r = 0; r < 4; ++r) {
            const int m = m0 + mt * 16 + quad * 4 + r;
            const int b = m >> 8, tok = m & 255;
#pragma unroll
            for (int nt = 0; nt < 4; ++nt) {
                const int c = n0 + nt * 16 + l15;
                const int rem = c - which * DIM_C;
                const int h = rem >> 5, d = rem & 31;
                const float val = (acc[mt][nt][r] + qkv_b[c]) * qscale;
                outp[((size_t)((b * NHEADS + h) * N_TOK + tok)) * HD + d] = f2bf(val);
            }
        }
    }
}

// ---------------------------------------------------------------------------
// Kernel 5: proj GEMM via MFMA, no LDS. out(65536,192) = ao(65536,192)*W^T + b.
// A already bf16; W pre-converted bf16; output fp32.
// ---------------------------------------------------------------------------
__global__ __launch_bounds__(256) void proj_gemm_kernel(
    const short* __restrict__ A16, const short* __restrict__ w16,
    const float* __restrict__ proj_b, float* __restrict__ out)
{
    const int t = threadIdx.x;
    const int lane = t & 63;
    const int w = t >> 6;
    const int l15 = lane & 15, quad = lane >> 4;
    const int n0 = blockIdx.x * 64;
    const int m0 = blockIdx.y * 128 + w * 32;

    f32x4 acc[2][4] = {};
#pragma unroll
    for (int ks = 0; ks < 6; ++ks) {
        bf16x8 af[2];
#pragma unroll
        for (int mt = 0; mt < 2; ++mt)
            af[mt] = *(const bf16x8*)(A16 + (size_t)(m0 + mt * 16 + l15) * DIM_C + ks * 32 + quad * 8);
        bf16x8 bfr[4];
#pragma unroll
        for (int nt = 0; nt < 4; ++nt)
            bfr[nt] = *(const bf16x8*)(w16 + (size_t)(n0 + nt * 16 + l15) * DIM_C + ks * 32 + quad * 8);
#pragma unroll
        for (int mt = 0; mt < 2; ++mt)
#pragma unroll
            for (int nt = 0; nt < 4; ++nt)
                acc[mt][nt] = __builtin_amdgcn_mfma_f32_16x16x32_bf16(af[mt], bfr[nt], acc[mt][nt], 0, 0, 0);
    }

#pragma unroll
    for (int mt = 0; mt < 2; ++mt) {
#pragma unroll
        for (int r = 0; r < 4; ++r) {
            const int m = m0 + mt * 16 + quad * 4 + r;
#pragma unroll
            for (int nt = 0; nt < 4; ++nt) {
                const int c = n0 + nt * 16 + l15;
                out[(size_t)m * DIM_C + c] = acc[mt][nt][r] + proj_b[c];
            }
        }
    }
}

// ---------------------------------------------------------------------------
// Kernel 4: MFMA attention per (b,h), all-bf16 I/O. 4 waves; wave w owns
// score cols [w*64,w*64+64). Two-pass softmax, P/V^T staged bf16 in LDS.
// ---------------------------------------------------------------------------
#define PS_LD 264   // 256 + 8 bf16 pad

__global__ __launch_bounds__(256) void attn_mfma_kernel(
    const short* __restrict__ q, const short* __restrict__ k,
    const short* __restrict__ v, const short* __restrict__ bias16,
    const short* __restrict__ mask16, short* __restrict__ out16)
{
    __shared__ __align__(16) short Vt[32][PS_LD];   // V^T [d][token]
    __shared__ __align__(16) short Ps[64][PS_LD];   // P chunk
    __shared__ __align__(16) float rowred[64][4];
    __shared__ __align__(16) float rowsum[64][4];

    const int h = blockIdx.x;            // 0..5
    const int b = blockIdx.y;            // 0..255
    const int t = threadIdx.x;
    const int lane = t & 63;
    const int w = t >> 6;
    const int l15 = lane & 15;
    const int quad = lane >> 4;
    const size_t slab = ((size_t)(b * NHEADS + h)) * (N_TOK * HD);

    // stage V^T (thread t -> token t)
    {
        const bf16x8* vrow = (const bf16x8*)(v + slab + (size_t)t * HD);
#pragma unroll
        for (int u = 0; u < 4; ++u) {
            bf16x8 vv = vrow[u];
#pragma unroll
            for (int j = 0; j < 8; ++j) Vt[u * 8 + j][t] = vv[j];
        }
    }

    // K fragments for this wave's 64 columns (whole kernel)
    bf16x8 kf[4];
#pragma unroll
    for (int nt = 0; nt < 4; ++nt)
        kf[nt] = *(const bf16x8*)(k + slab + (size_t)(w * 64 + nt * 16 + l15) * HD + quad * 8);
    __syncthreads();

    const short* biasH = bias16 + h * 65536;
    const short* maskW = mask16 + (size_t)(b & 63) * 65536;

    for (int chunk = 0; chunk < 4; ++chunk) {
        const int c0 = chunk * 64;

        bf16x8 qf[4];
#pragma unroll
        for (int mt = 0; mt < 4; ++mt)
            qf[mt] = *(const bf16x8*)(q + slab + (size_t)(c0 + mt * 16 + l15) * HD + quad * 8);

        f32x4 S[4][4];
#pragma unroll
        for (int mt = 0; mt < 4; ++mt)
#pragma unroll
            for (int nt = 0; nt < 4; ++nt) {
                f32x4 z = {0.f, 0.f, 0.f, 0.f};
                S[mt][nt] = __builtin_amdgcn_mfma_f32_16x16x32_bf16(qf[mt], kf[nt], z, 0, 0, 0);
            }

        // bias + mask + per-wave row max
#pragma unroll
        for (int mt = 0; mt < 4; ++mt) {
#pragma unroll
            for (int r = 0; r < 4; ++r) {
                const int row = c0 + mt * 16 + quad * 4 + r;
                const int colb = w * 64 + l15;
                float m4 = -1e30f;
#pragma unroll
                for (int nt = 0; nt < 4; ++nt) {
                    const int idx = row * 256 + colb + nt * 16;
                    float sval = S[mt][nt][r] + bf2f(biasH[idx]) + bf2f(maskW[idx]);
                    S[mt][nt][r] = sval;
                    m4 = fmaxf(m4, sval);
                }
                m4 = fmaxf(m4, __shfl_xor(m4, 1));
                m4 = fmaxf(m4, __shfl_xor(m4, 2));
                m4 = fmaxf(m4, __shfl_xor(m4, 4));
                m4 = fmaxf(m4, __shfl_xor(m4, 8));
                if (l15 == 0) rowred[mt * 16 + quad * 4 + r][w] = m4;
            }
        }
        __syncthreads();

        // exp + per-wave row sum + P -> LDS
#pragma unroll
        for (int mt = 0; mt < 4; ++mt) {
#pragma unroll
            for (int r = 0; r < 4; ++r) {
                const int lrow = mt * 16 + quad * 4 + r;
                float4 mr = *(const float4*)rowred[lrow];
                const float rm = fmaxf(fmaxf(mr.x, mr.y), fmaxf(mr.z, mr.w));
                float s4 = 0.0f;
#pragma unroll
                for (int nt = 0; nt < 4; ++nt) {
                    const float p = __expf(S[mt][nt][r] - rm);
                    s4 += p;
                    Ps[lrow][w * 64 + nt * 16 + l15] = f2bf(p);
                }
                s4 += __shfl_xor(s4, 1);
                s4 += __shfl_xor(s4, 2);
                s4 += __shfl_xor(s4, 4);
                s4 += __shfl_xor(s4, 8);
                if (l15 == 0) rowsum[lrow][w] = s4;
            }
        }
        __syncthreads();

        // PV: wave w -> rows w*16..w*16+15, all 32 d-cols
        f32x4 O0 = {0.f, 0.f, 0.f, 0.f};
        f32x4 O1 = {0.f, 0.f, 0.f, 0.f};
#pragma unroll
        for (int ks = 0; ks < 8; ++ks) {
            bf16x8 af  = *(const bf16x8*)&Ps[w * 16 + l15][ks * 32 + quad * 8];
            bf16x8 bf0 = *(const bf16x8*)&Vt[l15][ks * 32 + quad * 8];
            bf16x8 bf1 = *(const bf16x8*)&Vt[16 + l15][ks * 32 + quad * 8];
            O0 = __builtin_amdgcn_mfma_f32_16x16x32_bf16(af, bf0, O0, 0, 0, 0);
            O1 = __builtin_amdgcn_mfma_f32_16x16x32_bf16(af, bf1, O1, 0, 0, 0);
        }

#pragma unroll
        for (int r = 0; r < 4; ++r) {
            const int lrow = w * 16 + quad * 4 + r;
            float4 sr = *(const float4*)rowsum[lrow];
            const float inv = 1.0f / (sr.x + sr.y + sr.z + sr.w);
            const int token = c0 + lrow;
            short* dst = out16 + ((size_t)(b * N_TOK + token)) * DIM_C + h * HD;
            dst[l15]      = f2bf(O0[r] * inv);
            dst[16 + l15] = f2bf(O1[r] * inv);
        }
        __syncthreads();
    }
}

// ---------------------------------------------------------------------------
// Launch
// ---------------------------------------------------------------------------
extern "C" void kernel_launch(void* const* d_in, const int* in_sizes, int n_in,
                              void* d_out, int out_size, void* d_ws, size_t ws_size,
                              hipStream_t stream)
{
    const float* x      = (const float*)d_in[0];   // (256,256,192)
    const float* scale  = (const float*)d_in[1];   // (1,2)
    const float* mask   = (const float*)d_in[2];   // (64,256,256)
    const float* qkv_w  = (const float*)d_in[3];   // (576,192)
    const float* qkv_b  = (const float*)d_in[4];   // (576,)
    const float* cpb_w1 = (const float*)d_in[5];   // (512,4)
    const float* cpb_b1 = (const float*)d_in[6];   // (512,)
    const float* cpb_w2 = (const float*)d_in[7];   // (6,512)
    const float* cpb_b2 = (const float*)d_in[8];   // (6,)
    const float* proj_w = (const float*)d_in[9];   // (192,192)
    const float* proj_b = (const float*)d_in[10];  // (192,)
    float* out = (float*)d_out;                    // (256,256,192) fp32

    // Workspace (shorts): q,k,v,attn_out bf16 + mask16 + bias16 + w16s + table
    const size_t per = (size_t)B_WIN * NHEADS * N_TOK * HD;  // 12,582,912
    short* wss     = (short*)d_ws;
    short* qb      = wss;
    short* kb      = qb + per;
    short* vb      = kb + per;
    short* ao      = vb + per;
    short* mask16  = ao + per;                 // 64*65536   = 4,194,304
    short* bias16  = mask16 + 4194304;         // 6*65536    =   393,216
    short* qkvw16  = bias16 + 393216;          // 576*192    =   110,592
    short* projw16 = qkvw16 + 110592;          // 192*192    =    36,864
    float* table   = (float*)(projw16 + 36864);// 961*6 fp32

    cpb_table_kernel<<<961, 512, 0, stream>>>(scale, cpb_w1, cpb_b1, cpb_w2, cpb_b2, table);
    bias_expand_kernel<<<(NHEADS * 65536) / 256, 256, 0, stream>>>(table, bias16);

    f32_to_bf16_kernel<<<(4194304 / 4 + 255) / 256, 256, 0, stream>>>(mask, mask16, 4194304 / 4);
    f32_to_bf16_kernel<<<(110592 / 4 + 255) / 256, 256, 0, stream>>>(qkv_w, qkvw16, 110592 / 4);
    f32_to_bf16_kernel<<<(36864 / 4 + 255) / 256, 256, 0, stream>>>(proj_w, projw16, 36864 / 4);

    qkv_gemm_kernel<<<dim3(9, 512), 256, 0, stream>>>(x, qkvw16, qkv_b, qb, kb, vb);

    attn_mfma_kernel<<<dim3(NHEADS, B_WIN), 256, 0, stream>>>(qb, kb, vb, bias16, mask16, ao);

    proj_gemm_kernel<<<dim3(3, 512), 256, 0, stream>>>(ao, projw16, proj_b, out);
}

// Round 4
// 381.123 us; speedup vs baseline: 4.0458x; 1.8148x over previous
//
#include <hip/hip_runtime.h>
#include <math.h>

// Problem constants:
//   WH=WW=16, N=256 tokens/window, H=6 heads, DIM=192, hd=32
//   B_=256 windows, nW=64 mask windows, qk_scale = 32^-0.5
#define N_TOK 256
#define NHEADS 6
#define DIM_C 192
#define HD 32
#define B_WIN 256

typedef short bf16x8 __attribute__((ext_vector_type(8)));   // 8 bf16 in 4 VGPRs
typedef float f32x4 __attribute__((ext_vector_type(4)));

__device__ inline short f2bf(float f) {
    unsigned u = __float_as_uint(f);
    u = (u + 0x7fffu + ((u >> 16) & 1u)) >> 16;
    return (short)u;
}
__device__ inline float bf2f(short s) {
    return __uint_as_float(((unsigned)(unsigned short)s) << 16);
}

// ---------------------------------------------------------------------------
// Kernel 1: CPB MLP -> table (961 x 6) fp32
// ---------------------------------------------------------------------------
__global__ __launch_bounds__(512) void cpb_table_kernel(
    const float* __restrict__ scale, const float* __restrict__ w1,
    const float* __restrict__ b1, const float* __restrict__ w2,
    const float* __restrict__ b2, float* __restrict__ table)
{
    __shared__ float red[512];
    const int e = blockIdx.x;            // 0..960
    const int i = e / 31, j = e % 31;
    const float t0 = ((float)(i - 15)) * (8.0f / 15.0f);
    const float t1 = ((float)(j - 15)) * (8.0f / 15.0f);
    const float s0 = scale[0], s1 = scale[1];
    const int t = threadIdx.x;
    const float* w = w1 + t * 4;
    float h = w[0] * t0 + w[1] * t1 + w[2] * s0 + w[3] * s1 + b1[t];
    h = fmaxf(h, 0.0f);
    for (int head = 0; head < NHEADS; ++head) {
        red[t] = h * w2[head * 512 + t];
        __syncthreads();
        for (int s = 256; s > 0; s >>= 1) {
            if (t < s) red[t] += red[t + s];
            __syncthreads();
        }
        if (t == 0) table[e * NHEADS + head] = red[0] + b2[head];
        __syncthreads();
    }
}

// ---------------------------------------------------------------------------
// Kernel 2: combined bm[h][bw][row][col] = bias(h,row,col) + mask(bw,row,col)
// bf16 output, (6,64,256,256) = 50 MB. Each thread makes 8 consecutive cols.
// ---------------------------------------------------------------------------
__global__ __launch_bounds__(256) void bm_combine_kernel(
    const float* __restrict__ table, const float* __restrict__ mask,
    short* __restrict__ bm)
{
    const size_t g = (size_t)blockIdx.x * 256 + threadIdx.x;  // < 6*64*256*32
    const int col8 = (int)(g & 31);
    const int row  = (int)((g >> 5) & 255);
    const int bw   = (int)((g >> 13) & 63);
    const int h    = (int)(g >> 19);
    const float4* mp = (const float4*)(mask + ((size_t)bw << 16) + row * 256 + col8 * 8);
    float4 m0 = mp[0], m1 = mp[1];
    float mv[8] = {m0.x, m0.y, m0.z, m0.w, m1.x, m1.y, m1.z, m1.w};
    const int ri = row >> 4, rj = row & 15;
    bf16x8 r;
#pragma unroll
    for (int u = 0; u < 8; ++u) {
        const int col = col8 * 8 + u;
        const int rel0 = ri - (col >> 4) + 15;
        const int rel1 = rj - (col & 15) + 15;
        const float bias = table[(rel0 * 31 + rel1) * NHEADS + h];
        r[u] = f2bf(bias + mv[u]);
    }
    ((bf16x8*)bm)[g] = r;
}

// ---------------------------------------------------------------------------
// Kernel 2b: generic fp32 -> bf16 (n4 = count/4)
// ---------------------------------------------------------------------------
__global__ __launch_bounds__(256) void f32_to_bf16_kernel(
    const float* __restrict__ in, short* __restrict__ out, int n4)
{
    const int i = blockIdx.x * 256 + threadIdx.x;
    if (i < n4) {
        float4 v = ((const float4*)in)[i];
        short4 s;
        s.x = f2bf(v.x); s.y = f2bf(v.y); s.z = f2bf(v.z); s.w = f2bf(v.w);
        ((short4*)out)[i] = s;
    }
}

// ---------------------------------------------------------------------------
// Kernel 3: QKV GEMM via MFMA, no LDS. C(65536,576) = x16(65536,192)*W^T + b.
// A and W both bf16. Epilogue scatters bf16 into q/k/v (B,H,N,hd); q scaled.
// ---------------------------------------------------------------------------
__global__ __launch_bounds__(256) void qkv_gemm_kernel(
    const short* __restrict__ x16, const short* __restrict__ w16,
    const float* __restrict__ qkv_b,
    short* __restrict__ qb, short* __restrict__ kb, short* __restrict__ vb)
{
    const int t = threadIdx.x;
    const int lane = t & 63;
    const int w = t >> 6;
    const int l15 = lane & 15, quad = lane >> 4;
    const int n0 = blockIdx.x * 64;
    const int m0 = blockIdx.y * 128 + w * 32;

    f32x4 acc[2][4] = {};
#pragma unroll
    for (int ks = 0; ks < 6; ++ks) {
        bf16x8 af[2];
#pragma unroll
        for (int mt = 0; mt < 2; ++mt)
            af[mt] = *(const bf16x8*)(x16 + (size_t)(m0 + mt * 16 + l15) * DIM_C + ks * 32 + quad * 8);
        bf16x8 bfr[4];
#pragma unroll
        for (int nt = 0; nt < 4; ++nt)
            bfr[nt] = *(const bf16x8*)(w16 + (size_t)(n0 + nt * 16 + l15) * DIM_C + ks * 32 + quad * 8);
#pragma unroll
        for (int mt = 0; mt < 2; ++mt)
#pragma unroll
            for (int nt = 0; nt < 4; ++nt)
                acc[mt][nt] = __builtin_amdgcn_mfma_f32_16x16x32_bf16(af[mt], bfr[nt], acc[mt][nt], 0, 0, 0);
    }

    const int which = n0 / DIM_C;                   // constant per block
    short* outp = (which == 0) ? qb : (which == 1) ? kb : vb;
    const float qscale = (which == 0) ? 0.17677669529663689f : 1.0f;
#pragma unroll
    for (int mt = 0; mt < 2; ++mt) {
#pragma unroll
        for (int r = 0; r < 4; ++r) {
            const int m = m0 + mt * 16 + quad * 4 + r;
            const int b = m >> 8, tok = m & 255;
#pragma unroll
            for (int nt = 0; nt < 4; ++nt) {
                const int c = n0 + nt * 16 + l15;
                const int rem = c - which * DIM_C;
                const int h = rem >> 5, d = rem & 31;
                const float val = (acc[mt][nt][r] + qkv_b[c]) * qscale;
                outp[((size_t)((b * NHEADS + h) * N_TOK + tok)) * HD + d] = f2bf(val);
            }
        }
    }
}

// ---------------------------------------------------------------------------
// Kernel 5: proj GEMM via MFMA, no LDS. out(65536,192) = ao*W^T + b, fp32 out.
// ---------------------------------------------------------------------------
__global__ __launch_bounds__(256) void proj_gemm_kernel(
    const short* __restrict__ A16, const short* __restrict__ w16,
    const float* __restrict__ proj_b, float* __restrict__ out)
{
    const int t = threadIdx.x;
    const int lane = t & 63;
    const int w = t >> 6;
    const int l15 = lane & 15, quad = lane >> 4;
    const int n0 = blockIdx.x * 64;
    const int m0 = blockIdx.y * 128 + w * 32;

    f32x4 acc[2][4] = {};
#pragma unroll
    for (int ks = 0; ks < 6; ++ks) {
        bf16x8 af[2];
#pragma unroll
        for (int mt = 0; mt < 2; ++mt)
            af[mt] = *(const bf16x8*)(A16 + (size_t)(m0 + mt * 16 + l15) * DIM_C + ks * 32 + quad * 8);
        bf16x8 bfr[4];
#pragma unroll
        for (int nt = 0; nt < 4; ++nt)
            bfr[nt] = *(const bf16x8*)(w16 + (size_t)(n0 + nt * 16 + l15) * DIM_C + ks * 32 + quad * 8);
#pragma unroll
        for (int mt = 0; mt < 2; ++mt)
#pragma unroll
            for (int nt = 0; nt < 4; ++nt)
                acc[mt][nt] = __builtin_amdgcn_mfma_f32_16x16x32_bf16(af[mt], bfr[nt], acc[mt][nt], 0, 0, 0);
    }

#pragma unroll
    for (int mt = 0; mt < 2; ++mt) {
#pragma unroll
        for (int r = 0; r < 4; ++r) {
            const int m = m0 + mt * 16 + quad * 4 + r;
#pragma unroll
            for (int nt = 0; nt < 4; ++nt) {
                const int c = n0 + nt * 16 + l15;
                out[(size_t)m * DIM_C + c] = acc[mt][nt][r] + proj_b[c];
            }
        }
    }
}

// ---------------------------------------------------------------------------
// Kernel 4: MFMA attention per (b,h). 4 waves; wave w owns score cols
// [w*64,w*64+64). Per 64-row chunk: bm (bias+mask, bf16) is staged into the
// Ps LDS buffer with vector loads, consumed in the max phase via ds_read_u16,
// then Ps is overwritten with P for the PV MFMAs. V^T staged once.
// ---------------------------------------------------------------------------
#define PS_LD 264   // 256 + 8 bf16 pad

__global__ __launch_bounds__(256, 3) void attn_mfma_kernel(
    const short* __restrict__ q, const short* __restrict__ k,
    const short* __restrict__ v, const short* __restrict__ bm,
    short* __restrict__ out16)
{
    __shared__ __align__(16) short Vt[32][PS_LD];   // V^T [d][token]  16.9 KB
    __shared__ __align__(16) short Ps[64][PS_LD];   // bm chunk, then P  33.8 KB
    __shared__ __align__(16) float rowred[64][4];
    __shared__ __align__(16) float rowsum[64][4];

    const int h = blockIdx.x;            // 0..5
    const int b = blockIdx.y;            // 0..255
    const int t = threadIdx.x;
    const int lane = t & 63;
    const int w = t >> 6;
    const int l15 = lane & 15;
    const int quad = lane >> 4;
    const size_t slab = ((size_t)(b * NHEADS + h)) * (N_TOK * HD);

    // stage V^T (thread t -> token t)
    {
        const bf16x8* vrow = (const bf16x8*)(v + slab + (size_t)t * HD);
#pragma unroll
        for (int u = 0; u < 4; ++u) {
            bf16x8 vv = vrow[u];
#pragma unroll
            for (int j = 0; j < 8; ++j) Vt[u * 8 + j][t] = vv[j];
        }
    }

    // K fragments for this wave's 64 columns (persistent)
    bf16x8 kf[4];
#pragma unroll
    for (int nt = 0; nt < 4; ++nt)
        kf[nt] = *(const bf16x8*)(k + slab + (size_t)(w * 64 + nt * 16 + l15) * HD + quad * 8);

    const short* bmB = bm + (((size_t)h * 64 + (b & 63)) << 16);
    const int srow = t >> 2;             // staging row 0..63
    const int scol = (t & 3) * 64;       // staging col base

    __syncthreads();   // Vt ready

    for (int chunk = 0; chunk < 4; ++chunk) {
        const int c0 = chunk * 64;

        // phase 1: stage bm chunk (64x256 bf16 = 32 KB) into Ps, coalesced
        {
            const bf16x8* src = (const bf16x8*)(bmB + (size_t)(c0 + srow) * 256 + scol);
#pragma unroll
            for (int u = 0; u < 8; ++u)
                *(bf16x8*)&Ps[srow][scol + u * 8] = src[u];
        }

        // Q fragments (independent of LDS -> overlap the barrier)
        bf16x8 qf[4];
#pragma unroll
        for (int mt = 0; mt < 4; ++mt)
            qf[mt] = *(const bf16x8*)(q + slab + (size_t)(c0 + mt * 16 + l15) * HD + quad * 8);
        __syncthreads();   // bm staged

        // QK^T: 16 MFMAs (row = mt*16+quad*4+r, col = w*64+nt*16+l15)
        f32x4 S[4][4];
#pragma unroll
        for (int mt = 0; mt < 4; ++mt)
#pragma unroll
            for (int nt = 0; nt < 4; ++nt) {
                f32x4 z = {0.f, 0.f, 0.f, 0.f};
                S[mt][nt] = __builtin_amdgcn_mfma_f32_16x16x32_bf16(qf[mt], kf[nt], z, 0, 0, 0);
            }

        // phase 3: add bm (from LDS), per-wave row max
#pragma unroll
        for (int mt = 0; mt < 4; ++mt) {
#pragma unroll
            for (int r = 0; r < 4; ++r) {
                const int lrow = mt * 16 + quad * 4 + r;
                float m4 = -1e30f;
#pragma unroll
                for (int nt = 0; nt < 4; ++nt) {
                    float sval = S[mt][nt][r] + bf2f(Ps[lrow][w * 64 + nt * 16 + l15]);
                    S[mt][nt][r] = sval;
                    m4 = fmaxf(m4, sval);
                }
                m4 = fmaxf(m4, __shfl_xor(m4, 1));
                m4 = fmaxf(m4, __shfl_xor(m4, 2));
                m4 = fmaxf(m4, __shfl_xor(m4, 4));
                m4 = fmaxf(m4, __shfl_xor(m4, 8));
                if (l15 == 0) rowred[lrow][w] = m4;
            }
        }
        __syncthreads();   // bm fully consumed; rowred ready

        // phase 4: exp + per-wave row sum + P -> Ps (overwrite bm)
#pragma unroll
        for (int mt = 0; mt < 4; ++mt) {
#pragma unroll
            for (int r = 0; r < 4; ++r) {
                const int lrow = mt * 16 + quad * 4 + r;
                float4 mr = *(const float4*)rowred[lrow];
                const float rm = fmaxf(fmaxf(mr.x, mr.y), fmaxf(mr.z, mr.w));
                float s4 = 0.0f;
#pragma unroll
                for (int nt = 0; nt < 4; ++nt) {
                    const float p = __expf(S[mt][nt][r] - rm);
                    s4 += p;
                    Ps[lrow][w * 64 + nt * 16 + l15] = f2bf(p);
                }
                s4 += __shfl_xor(s4, 1);
                s4 += __shfl_xor(s4, 2);
                s4 += __shfl_xor(s4, 4);
                s4 += __shfl_xor(s4, 8);
                if (l15 == 0) rowsum[lrow][w] = s4;
            }
        }
        __syncthreads();   // P + rowsum ready

        // PV: wave w -> rows w*16..w*16+15, all 32 d-cols
        f32x4 O0 = {0.f, 0.f, 0.f, 0.f};
        f32x4 O1 = {0.f, 0.f, 0.f, 0.f};
#pragma unroll
        for (int ks = 0; ks < 8; ++ks) {
            bf16x8 af  = *(const bf16x8*)&Ps[w * 16 + l15][ks * 32 + quad * 8];
            bf16x8 bf0 = *(const bf16x8*)&Vt[l15][ks * 32 + quad * 8];
            bf16x8 bf1 = *(const bf16x8*)&Vt[16 + l15][ks * 32 + quad * 8];
            O0 = __builtin_amdgcn_mfma_f32_16x16x32_bf16(af, bf0, O0, 0, 0, 0);
            O1 = __builtin_amdgcn_mfma_f32_16x16x32_bf16(af, bf1, O1, 0, 0, 0);
        }

#pragma unroll
        for (int r = 0; r < 4; ++r) {
            const int lrow = w * 16 + quad * 4 + r;
            float4 sr = *(const float4*)rowsum[lrow];
            const float inv = 1.0f / (sr.x + sr.y + sr.z + sr.w);
            const int token = c0 + lrow;
            short* dst = out16 + ((size_t)(b * N_TOK + token)) * DIM_C + h * HD;
            dst[l15]      = f2bf(O0[r] * inv);
            dst[16 + l15] = f2bf(O1[r] * inv);
        }
        __syncthreads();   // protect Ps/rowred/rowsum before next chunk
    }
}

// ---------------------------------------------------------------------------
// Launch
// ---------------------------------------------------------------------------
extern "C" void kernel_launch(void* const* d_in, const int* in_sizes, int n_in,
                              void* d_out, int out_size, void* d_ws, size_t ws_size,
                              hipStream_t stream)
{
    const float* x      = (const float*)d_in[0];   // (256,256,192)
    const float* scale  = (const float*)d_in[1];   // (1,2)
    const float* mask   = (const float*)d_in[2];   // (64,256,256)
    const float* qkv_w  = (const float*)d_in[3];   // (576,192)
    const float* qkv_b  = (const float*)d_in[4];   // (576,)
    const float* cpb_w1 = (const float*)d_in[5];   // (512,4)
    const float* cpb_b1 = (const float*)d_in[6];   // (512,)
    const float* cpb_w2 = (const float*)d_in[7];   // (6,512)
    const float* cpb_b2 = (const float*)d_in[8];   // (6,)
    const float* proj_w = (const float*)d_in[9];   // (192,192)
    const float* proj_b = (const float*)d_in[10];  // (192,)
    float* out = (float*)d_out;                    // (256,256,192) fp32

    // Workspace (shorts): q,k,v,ao,x16 bf16 + bm + weights + table
    const size_t per = (size_t)B_WIN * NHEADS * N_TOK * HD;  // 12,582,912
    short* wss     = (short*)d_ws;
    short* qb      = wss;
    short* kb      = qb + per;
    short* vb      = kb + per;
    short* ao      = vb + per;
    short* x16     = ao + per;                    // 12,582,912
    short* bmbuf   = x16 + per;                   // 6*64*65536 = 25,165,824
    short* qkvw16  = bmbuf + 25165824;            // 110,592
    short* projw16 = qkvw16 + 110592;             // 36,864
    float* table   = (float*)(projw16 + 36864);   // 961*6 fp32

    cpb_table_kernel<<<961, 512, 0, stream>>>(scale, cpb_w1, cpb_b1, cpb_w2, cpb_b2, table);

    bm_combine_kernel<<<(NHEADS * 64 * 256 * 32) / 256, 256, 0, stream>>>(table, mask, bmbuf);

    f32_to_bf16_kernel<<<(int)((per / 4 + 255) / 256), 256, 0, stream>>>(x, x16, (int)(per / 4));
    f32_to_bf16_kernel<<<(110592 / 4 + 255) / 256, 256, 0, stream>>>(qkv_w, qkvw16, 110592 / 4);
    f32_to_bf16_kernel<<<(36864 / 4 + 255) / 256, 256, 0, stream>>>(proj_w, projw16, 36864 / 4);

    qkv_gemm_kernel<<<dim3(9, 512), 256, 0, stream>>>(x16, qkvw16, qkv_b, qb, kb, vb);

    attn_mfma_kernel<<<dim3(NHEADS, B_WIN), 256, 0, stream>>>(qb, kb, vb, bmbuf, ao);

    proj_gemm_kernel<<<dim3(3, 512), 256, 0, stream>>>(ao, projw16, proj_b, out);
}

// Round 5
// 361.887 us; speedup vs baseline: 4.2609x; 1.0532x over previous
//
#include <hip/hip_runtime.h>
#include <math.h>

// Problem constants:
//   WH=WW=16, N=256 tokens/window, H=6 heads, DIM=192, hd=32
//   B_=256 windows, nW=64 mask windows, qk_scale = 32^-0.5
#define N_TOK 256
#define NHEADS 6
#define DIM_C 192
#define HD 32
#define B_WIN 256

typedef short bf16x8 __attribute__((ext_vector_type(8)));   // 8 bf16 in 4 VGPRs
typedef float f32x4 __attribute__((ext_vector_type(4)));

__device__ inline short f2bf(float f) {          // RNE
    unsigned u = __float_as_uint(f);
    u = (u + 0x7fffu + ((u >> 16) & 1u)) >> 16;
    return (short)u;
}
__device__ inline short f2bf_fast(float f) {     // round-half-up (0.5 ulp)
    return (short)((__float_as_uint(f) + 0x8000u) >> 16);
}
__device__ inline float bf2f(short s) {
    return __uint_as_float(((unsigned)(unsigned short)s) << 16);
}

// ---------------------------------------------------------------------------
// Kernel 1: CPB MLP -> table (961 x 6) fp32
// ---------------------------------------------------------------------------
__global__ __launch_bounds__(512) void cpb_table_kernel(
    const float* __restrict__ scale, const float* __restrict__ w1,
    const float* __restrict__ b1, const float* __restrict__ w2,
    const float* __restrict__ b2, float* __restrict__ table)
{
    __shared__ float red[512];
    const int e = blockIdx.x;            // 0..960
    const int i = e / 31, j = e % 31;
    const float t0 = ((float)(i - 15)) * (8.0f / 15.0f);
    const float t1 = ((float)(j - 15)) * (8.0f / 15.0f);
    const float s0 = scale[0], s1 = scale[1];
    const int t = threadIdx.x;
    const float* w = w1 + t * 4;
    float h = w[0] * t0 + w[1] * t1 + w[2] * s0 + w[3] * s1 + b1[t];
    h = fmaxf(h, 0.0f);
    for (int head = 0; head < NHEADS; ++head) {
        red[t] = h * w2[head * 512 + t];
        __syncthreads();
        for (int s = 256; s > 0; s >>= 1) {
            if (t < s) red[t] += red[t + s];
            __syncthreads();
        }
        if (t == 0) table[e * NHEADS + head] = red[0] + b2[head];
        __syncthreads();
    }
}

// ---------------------------------------------------------------------------
// MFMA-C-layout permuted index helper. Slab layout (65536 bf16):
//   offset = ((rb*8 + g)*64 + lane)*8 + (nt&1)*4 + r
//   where row = rb*16 + (lane>>4)*4 + r,  col = nt*16 + (lane&15),  nt = 2g+(j>>2)
// Thread j in [0,8): nt = 2g + (j>>2), r = j&3.
// ---------------------------------------------------------------------------

// Kernel 2a: bias -> permuted bf16 (6 slabs). One thread per 8 outputs.
__global__ __launch_bounds__(256) void bias_perm_kernel(
    const float* __restrict__ table, short* __restrict__ bias_p)
{
    const int idx8 = blockIdx.x * 256 + threadIdx.x;   // < 6*8192
    const int h = idx8 >> 13;
    const int rem = idx8 & 8191;
    const int rb = rem >> 9;
    const int g = (rem >> 6) & 7;
    const int lane = rem & 63;
    const int quad = lane >> 4, l15 = lane & 15;
    bf16x8 o;
#pragma unroll
    for (int j = 0; j < 8; ++j) {
        const int nt = g * 2 + (j >> 2), r = j & 3;
        const int row = rb * 16 + quad * 4 + r;
        const int col = nt * 16 + l15;
        const int rel0 = (row >> 4) - (col >> 4) + 15;
        const int rel1 = (row & 15) - (col & 15) + 15;
        o[j] = f2bf(table[(rel0 * 31 + rel1) * NHEADS + h]);
    }
    ((bf16x8*)bias_p)[idx8] = o;
}

// Kernel 2b: mask -> permuted bf16 (64 slabs).
__global__ __launch_bounds__(256) void mask_perm_kernel(
    const float* __restrict__ mask, short* __restrict__ mask_p)
{
    const int idx8 = blockIdx.x * 256 + threadIdx.x;   // < 64*8192
    const int bw = idx8 >> 13;
    const int rem = idx8 & 8191;
    const int rb = rem >> 9;
    const int g = (rem >> 6) & 7;
    const int lane = rem & 63;
    const int quad = lane >> 4, l15 = lane & 15;
    const float* ms = mask + ((size_t)bw << 16);
    bf16x8 o;
#pragma unroll
    for (int j = 0; j < 8; ++j) {
        const int nt = g * 2 + (j >> 2), r = j & 3;
        const int row = rb * 16 + quad * 4 + r;
        const int col = nt * 16 + l15;
        o[j] = f2bf(ms[row * 256 + col]);
    }
    ((bf16x8*)mask_p)[idx8] = o;
}

// ---------------------------------------------------------------------------
// Kernel 2c: generic fp32 -> bf16 (n4 = count/4)
// ---------------------------------------------------------------------------
__global__ __launch_bounds__(256) void f32_to_bf16_kernel(
    const float* __restrict__ in, short* __restrict__ out, int n4)
{
    const int i = blockIdx.x * 256 + threadIdx.x;
    if (i < n4) {
        float4 v = ((const float4*)in)[i];
        short4 s;
        s.x = f2bf(v.x); s.y = f2bf(v.y); s.z = f2bf(v.z); s.w = f2bf(v.w);
        ((short4*)out)[i] = s;
    }
}

// ---------------------------------------------------------------------------
// Kernel 3: QKV GEMM via MFMA, no LDS. C(65536,576) = x16(65536,192)*W^T + b.
// ---------------------------------------------------------------------------
__global__ __launch_bounds__(256) void qkv_gemm_kernel(
    const short* __restrict__ x16, const short* __restrict__ w16,
    const float* __restrict__ qkv_b,
    short* __restrict__ qb, short* __restrict__ kb, short* __restrict__ vb)
{
    const int t = threadIdx.x;
    const int lane = t & 63;
    const int w = t >> 6;
    const int l15 = lane & 15, quad = lane >> 4;
    const int n0 = blockIdx.x * 64;
    const int m0 = blockIdx.y * 128 + w * 32;

    f32x4 acc[2][4] = {};
#pragma unroll
    for (int ks = 0; ks < 6; ++ks) {
        bf16x8 af[2];
#pragma unroll
        for (int mt = 0; mt < 2; ++mt)
            af[mt] = *(const bf16x8*)(x16 + (size_t)(m0 + mt * 16 + l15) * DIM_C + ks * 32 + quad * 8);
        bf16x8 bfr[4];
#pragma unroll
        for (int nt = 0; nt < 4; ++nt)
            bfr[nt] = *(const bf16x8*)(w16 + (size_t)(n0 + nt * 16 + l15) * DIM_C + ks * 32 + quad * 8);
#pragma unroll
        for (int mt = 0; mt < 2; ++mt)
#pragma unroll
            for (int nt = 0; nt < 4; ++nt)
                acc[mt][nt] = __builtin_amdgcn_mfma_f32_16x16x32_bf16(af[mt], bfr[nt], acc[mt][nt], 0, 0, 0);
    }

    const int which = n0 / DIM_C;                   // constant per block
    short* outp = (which == 0) ? qb : (which == 1) ? kb : vb;
    const float qscale = (which == 0) ? 0.17677669529663689f : 1.0f;
#pragma unroll
    for (int mt = 0; mt < 2; ++mt) {
#pragma unroll
        for (int r = 0; r < 4; ++r) {
            const int m = m0 + mt * 16 + quad * 4 + r;
            const int b = m >> 8, tok = m & 255;
#pragma unroll
            for (int nt = 0; nt < 4; ++nt) {
                const int c = n0 + nt * 16 + l15;
                const int rem = c - which * DIM_C;
                const int h = rem >> 5, d = rem & 31;
                const float val = (acc[mt][nt][r] + qkv_b[c]) * qscale;
                outp[((size_t)((b * NHEADS + h) * N_TOK + tok)) * HD + d] = f2bf(val);
            }
        }
    }
}

// ---------------------------------------------------------------------------
// Kernel 5: proj GEMM via MFMA, no LDS. out(65536,192) = ao*W^T + b, fp32 out.
// ---------------------------------------------------------------------------
__global__ __launch_bounds__(256) void proj_gemm_kernel(
    const short* __restrict__ A16, const short* __restrict__ w16,
    const float* __restrict__ proj_b, float* __restrict__ out)
{
    const int t = threadIdx.x;
    const int lane = t & 63;
    const int w = t >> 6;
    const int l15 = lane & 15, quad = lane >> 4;
    const int n0 = blockIdx.x * 64;
    const int m0 = blockIdx.y * 128 + w * 32;

    f32x4 acc[2][4] = {};
#pragma unroll
    for (int ks = 0; ks < 6; ++ks) {
        bf16x8 af[2];
#pragma unroll
        for (int mt = 0; mt < 2; ++mt)
            af[mt] = *(const bf16x8*)(A16 + (size_t)(m0 + mt * 16 + l15) * DIM_C + ks * 32 + quad * 8);
        bf16x8 bfr[4];
#pragma unroll
        for (int nt = 0; nt < 4; ++nt)
            bfr[nt] = *(const bf16x8*)(w16 + (size_t)(n0 + nt * 16 + l15) * DIM_C + ks * 32 + quad * 8);
#pragma unroll
        for (int mt = 0; mt < 2; ++mt)
#pragma unroll
            for (int nt = 0; nt < 4; ++nt)
                acc[mt][nt] = __builtin_amdgcn_mfma_f32_16x16x32_bf16(af[mt], bfr[nt], acc[mt][nt], 0, 0, 0);
    }

#pragma unroll
    for (int mt = 0; mt < 2; ++mt) {
#pragma unroll
        for (int r = 0; r < 4; ++r) {
            const int m = m0 + mt * 16 + quad * 4 + r;
#pragma unroll
            for (int nt = 0; nt < 4; ++nt) {
                const int c = n0 + nt * 16 + l15;
                out[(size_t)m * DIM_C + c] = acc[mt][nt][r] + proj_b[c];
            }
        }
    }
}

// ---------------------------------------------------------------------------
// Kernel 4: MFMA attention per (b,h), wave-owns-rows structure.
// 4 waves; wave w + chunk c handles row block rb = c*4+w (16 rows x 256 cols).
// Softmax reductions are pure in-wave shfl; P goes to a per-wave LDS region
// (no __syncthreads in the chunk loop). bias/mask read directly from global
// in pre-permuted MFMA C-layout. XOR-16 swizzle on Vt/Ps columns kills the
// 4-way bank conflicts (quads -> bank groups +0/+16/+8/+24).
// ---------------------------------------------------------------------------
#define PS_LD 264   // shorts; 528 B/row (16B aligned)

__global__ __launch_bounds__(256, 3) void attn_mfma_kernel(
    const short* __restrict__ q, const short* __restrict__ k,
    const short* __restrict__ v, const short* __restrict__ bias_p,
    const short* __restrict__ mask_p, short* __restrict__ out16)
{
    __shared__ __align__(16) short Vt[32][PS_LD];      // V^T, 16.9 KB
    __shared__ __align__(16) short Pw[4][16][PS_LD];   // per-wave P, 33.8 KB

    const int h = blockIdx.x;            // 0..5
    const int b = blockIdx.y;            // 0..255
    const int t = threadIdx.x;
    const int lane = t & 63;
    const int w = t >> 6;
    const int l15 = lane & 15;
    const int quad = lane >> 4;
    const size_t slab = ((size_t)(b * NHEADS + h)) * (N_TOK * HD);

    // stage V^T (thread t -> token t), swizzled columns
    {
        const bf16x8* vrow = (const bf16x8*)(v + slab + (size_t)t * HD);
#pragma unroll
        for (int u = 0; u < 4; ++u) {
            bf16x8 vv = vrow[u];
#pragma unroll
            for (int j = 0; j < 8; ++j) {
                const int d = u * 8 + j;
                Vt[d][t ^ (((d >> 3) & 1) * 16)] = vv[j];
            }
        }
    }
    __syncthreads();   // Vt ready (only barrier in the kernel body)

    const short* bslab = bias_p + h * 65536;
    const short* mslab = mask_p + ((b & 63) * 65536);

    for (int chunk = 0; chunk < 4; ++chunk) {
        const int rb = chunk * 4 + w;    // row block 0..15

        // Q fragment: rows rb*16 + l15, k = quad*8..+7
        const bf16x8 qf = *(const bf16x8*)(q + slab + (size_t)(rb * 16 + l15) * HD + quad * 8);

        // QK^T: 16 MFMAs -> S[nt], C-layout: row = rb*16+quad*4+r, col = nt*16+l15
        f32x4 S[16];
#pragma unroll
        for (int nt = 0; nt < 16; ++nt) {
            const bf16x8 kf = *(const bf16x8*)(k + slab + (size_t)(nt * 16 + l15) * HD + quad * 8);
            f32x4 z = {0.f, 0.f, 0.f, 0.f};
            S[nt] = __builtin_amdgcn_mfma_f32_16x16x32_bf16(qf, kf, z, 0, 0, 0);
        }

        // add bias+mask (permuted direct loads), in two register halves
        float mx[4] = {-1e30f, -1e30f, -1e30f, -1e30f};
#pragma unroll
        for (int half = 0; half < 2; ++half) {
            bf16x8 bb[4], mm[4];
#pragma unroll
            for (int gg = 0; gg < 4; ++gg) {
                const int g = half * 4 + gg;
                const int off = ((rb * 8 + g) * 64 + lane) * 8;
                bb[gg] = *(const bf16x8*)(bslab + off);
                mm[gg] = *(const bf16x8*)(mslab + off);
            }
#pragma unroll
            for (int gg = 0; gg < 4; ++gg) {
#pragma unroll
                for (int jj = 0; jj < 8; ++jj) {
                    const int nt = (half * 4 + gg) * 2 + (jj >> 2);
                    const int r = jj & 3;
                    const float sv = S[nt][r] + bf2f(bb[gg][jj]) + bf2f(mm[gg][jj]);
                    S[nt][r] = sv;
                    mx[r] = fmaxf(mx[r], sv);
                }
            }
        }

        // row max across l15 lanes (rows = quad*4+r, full 256 cols)
#pragma unroll
        for (int r = 0; r < 4; ++r) {
            mx[r] = fmaxf(mx[r], __shfl_xor(mx[r], 1));
            mx[r] = fmaxf(mx[r], __shfl_xor(mx[r], 2));
            mx[r] = fmaxf(mx[r], __shfl_xor(mx[r], 4));
            mx[r] = fmaxf(mx[r], __shfl_xor(mx[r], 8));
        }

        // exp + row sum + P -> per-wave LDS (swizzled)
        float sm[4] = {0.f, 0.f, 0.f, 0.f};
#pragma unroll
        for (int nt = 0; nt < 16; ++nt) {
#pragma unroll
            for (int r = 0; r < 4; ++r) {
                const float p = __expf(S[nt][r] - mx[r]);
                sm[r] += p;
                const int lr = quad * 4 + r;
                Pw[w][lr][(nt * 16 + l15) ^ (((lr >> 3) & 1) * 16)] = f2bf_fast(p);
            }
        }
        float inv[4];
#pragma unroll
        for (int r = 0; r < 4; ++r) {
            sm[r] += __shfl_xor(sm[r], 1);
            sm[r] += __shfl_xor(sm[r], 2);
            sm[r] += __shfl_xor(sm[r], 4);
            sm[r] += __shfl_xor(sm[r], 8);
            inv[r] = __builtin_amdgcn_rcpf(sm[r]);
        }

        // wave-local LDS: drain writes before fragment reads
        __asm__ volatile("s_waitcnt lgkmcnt(0)" ::: "memory");

        // PV: O (16 rows x 32 d), A-frags from own Pw, B-frags from Vt
        f32x4 O0 = {0.f, 0.f, 0.f, 0.f};
        f32x4 O1 = {0.f, 0.f, 0.f, 0.f};
        const int sw = ((l15 >> 3) & 1) * 16;
#pragma unroll
        for (int ks = 0; ks < 8; ++ks) {
            const int cb = ks * 32 + quad * 8;
            bf16x8 af  = *(const bf16x8*)&Pw[w][l15][cb ^ sw];
            bf16x8 bf0 = *(const bf16x8*)&Vt[l15][cb ^ sw];
            bf16x8 bf1 = *(const bf16x8*)&Vt[16 + l15][cb ^ sw];
            O0 = __builtin_amdgcn_mfma_f32_16x16x32_bf16(af, bf0, O0, 0, 0, 0);
            O1 = __builtin_amdgcn_mfma_f32_16x16x32_bf16(af, bf1, O1, 0, 0, 0);
        }

        // epilogue: rows quad*4+r match this thread's inv[r]
#pragma unroll
        for (int r = 0; r < 4; ++r) {
            const int token = rb * 16 + quad * 4 + r;
            short* dst = out16 + ((size_t)(b * N_TOK + token)) * DIM_C + h * HD;
            dst[l15]      = f2bf_fast(O0[r] * inv[r]);
            dst[16 + l15] = f2bf_fast(O1[r] * inv[r]);
        }
    }
}

// ---------------------------------------------------------------------------
// Launch
// ---------------------------------------------------------------------------
extern "C" void kernel_launch(void* const* d_in, const int* in_sizes, int n_in,
                              void* d_out, int out_size, void* d_ws, size_t ws_size,
                              hipStream_t stream)
{
    const float* x      = (const float*)d_in[0];   // (256,256,192)
    const float* scale  = (const float*)d_in[1];   // (1,2)
    const float* mask   = (const float*)d_in[2];   // (64,256,256)
    const float* qkv_w  = (const float*)d_in[3];   // (576,192)
    const float* qkv_b  = (const float*)d_in[4];   // (576,)
    const float* cpb_w1 = (const float*)d_in[5];   // (512,4)
    const float* cpb_b1 = (const float*)d_in[6];   // (512,)
    const float* cpb_w2 = (const float*)d_in[7];   // (6,512)
    const float* cpb_b2 = (const float*)d_in[8];   // (6,)
    const float* proj_w = (const float*)d_in[9];   // (192,192)
    const float* proj_b = (const float*)d_in[10];  // (192,)
    float* out = (float*)d_out;                    // (256,256,192) fp32

    const size_t per = (size_t)B_WIN * NHEADS * N_TOK * HD;  // 12,582,912
    short* wss     = (short*)d_ws;
    short* qb      = wss;
    short* kb      = qb + per;
    short* vb      = kb + per;
    short* ao      = vb + per;
    short* x16     = ao + per;                    // 12,582,912
    short* bias_p  = x16 + per;                   // 6*65536  =   393,216
    short* mask_p  = bias_p + 393216;             // 64*65536 = 4,194,304
    short* qkvw16  = mask_p + 4194304;            // 110,592
    short* projw16 = qkvw16 + 110592;             // 36,864
    float* table   = (float*)(projw16 + 36864);   // 961*6 fp32

    cpb_table_kernel<<<961, 512, 0, stream>>>(scale, cpb_w1, cpb_b1, cpb_w2, cpb_b2, table);

    bias_perm_kernel<<<(NHEADS * 8192) / 256, 256, 0, stream>>>(table, bias_p);
    mask_perm_kernel<<<(64 * 8192) / 256, 256, 0, stream>>>(mask, mask_p);

    f32_to_bf16_kernel<<<(int)((per / 4 + 255) / 256), 256, 0, stream>>>(x, x16, (int)(per / 4));
    f32_to_bf16_kernel<<<(110592 / 4 + 255) / 256, 256, 0, stream>>>(qkv_w, qkvw16, 110592 / 4);
    f32_to_bf16_kernel<<<(36864 / 4 + 255) / 256, 256, 0, stream>>>(proj_w, projw16, 36864 / 4);

    qkv_gemm_kernel<<<dim3(9, 512), 256, 0, stream>>>(x16, qkvw16, qkv_b, qb, kb, vb);

    attn_mfma_kernel<<<dim3(NHEADS, B_WIN), 256, 0, stream>>>(qb, kb, vb, bias_p, mask_p, ao);

    proj_gemm_kernel<<<dim3(3, 512), 256, 0, stream>>>(ao, projw16, proj_b, out);
}